// Round 25
// baseline (707.555 us; speedup 1.0000x reference)
//
#include <hip/hip_runtime.h>
#include <hip/hip_fp16.h>

#define NN 50000
#define NE 1600000
#define F 32
#define T 4
#define FT 8
#define ED 16
#define NLAYERS 5

typedef _Float16 h2 __attribute__((ext_vector_type(2)));

__device__ __forceinline__ float dot2(h2 a, h2 b, float c) {
#if __has_builtin(__builtin_amdgcn_fdot2)
    return __builtin_amdgcn_fdot2(a, b, c, false);
#else
    return c + (float)a.x * (float)b.x + (float)a.y * (float)b.y;
#endif
}

// ---------------- CSR build (once per call; edge_index constant across layers) ----

__global__ void zero_cnt(int* __restrict__ cnt) {
    int i = blockIdx.x * 256 + threadIdx.x;
    if (i < NN) cnt[i] = 0;
}

__global__ void count_kernel(const int* __restrict__ ei, int* __restrict__ cnt) {
    int e = blockIdx.x * 256 + threadIdx.x;
    if (e >= NE) return;
    atomicAdd(&cnt[ei[NE + e]], 1);
}

// one-block exclusive scan over cnt[NN] -> row_ptr, cursor (1024 threads)
__global__ void scan_kernel(const int* __restrict__ cnt, int* __restrict__ row_ptr,
                            int* __restrict__ cursor) {
    __shared__ int wsum[16];
    __shared__ int carry_s;
    int tid = threadIdx.x;
    int lane = tid & 63, wid = tid >> 6;
    if (tid == 0) carry_s = 0;
    __syncthreads();
    for (int base = 0; base < NN; base += 1024) {
        int i = base + tid;
        int v = (i < NN) ? cnt[i] : 0;
        int s = v;
#pragma unroll
        for (int off = 1; off < 64; off <<= 1) {
            int tt = __shfl_up(s, off, 64);
            if (lane >= off) s += tt;
        }
        __syncthreads();
        if (lane == 63) wsum[wid] = s;
        __syncthreads();
        if (wid == 0 && lane < 16) {
            int w = wsum[lane];
            int ws = w;
#pragma unroll
            for (int off = 1; off < 16; off <<= 1) {
                int tt = __shfl_up(ws, off, 16);
                if (lane >= off) ws += tt;
            }
            wsum[lane] = ws - w;
        }
        __syncthreads();
        int excl = carry_s + wsum[wid] + s - v;
        if (i < NN) { row_ptr[i] = excl; cursor[i] = excl; }
        __syncthreads();
        if (tid == 1023) carry_s += wsum[15] + s;
    }
}

// fused scatter: read eattr SEQUENTIALLY, compute CSR slot p, write src*32 + fp16 eattr.
__global__ void build_kernel(const int* __restrict__ ei,
                             const float* __restrict__ eattr,
                             int* __restrict__ cursor,
                             int* __restrict__ src_s,     // stores src*F (element offset)
                             float4* __restrict__ eh) {   // [NE][2] float4 (=16 half)
    int e = blockIdx.x * 256 + threadIdx.x;
    if (e >= NE) return;
    int src = ei[e];
    int dst = ei[NE + e];
    const float4* eap = (const float4*)(eattr + (size_t)e * ED);
    float4 v0 = eap[0], v1 = eap[1], v2 = eap[2], v3 = eap[3];
    union { __half hh[16]; float4 f4[2]; } u;
    u.hh[0]  = __float2half(v0.x); u.hh[1]  = __float2half(v0.y);
    u.hh[2]  = __float2half(v0.z); u.hh[3]  = __float2half(v0.w);
    u.hh[4]  = __float2half(v1.x); u.hh[5]  = __float2half(v1.y);
    u.hh[6]  = __float2half(v1.z); u.hh[7]  = __float2half(v1.w);
    u.hh[8]  = __float2half(v2.x); u.hh[9]  = __float2half(v2.y);
    u.hh[10] = __float2half(v2.z); u.hh[11] = __float2half(v2.w);
    u.hh[12] = __float2half(v3.x); u.hh[13] = __float2half(v3.y);
    u.hh[14] = __float2half(v3.z); u.hh[15] = __float2half(v3.w);
    int p = atomicAdd(&cursor[dst], 1);
    src_s[p] = src << 5;   // src * F
    eh[2 * (size_t)p]     = u.f4[0];
    eh[2 * (size_t)p + 1] = u.f4[1];
}

// per-layer constants: wchp[(l*32+ch)] = packed fp16 wc16 (16 halfs = 2 float4);
// abias[l*32+ch] = preb + ebias . preW_ee
__global__ void layer_const(const float* __restrict__ edge_W,  // [L,16,8]
                            const float* __restrict__ edge_b,  // [L,8]
                            const float* __restrict__ pre_W,   // [L,T,24,8]
                            const float* __restrict__ pre_b,   // [L,T,8]
                            float4* __restrict__ wchp,         // [L*32][2]
                            float* __restrict__ abias) {       // [L*32]
    int idx = threadIdx.x;
    if (idx >= NLAYERS * 32) return;
    int l = idx >> 5, ch = idx & 31;
    int t = ch >> 3, f = ch & 7;
    const float* eW = edge_W + (size_t)l * ED * FT;
    const float* eb = edge_b + (size_t)l * FT;
    const float* pW = pre_W + (size_t)l * T * 24 * FT;
    const float* pb = pre_b + (size_t)l * T * FT;
    float pj[8];
#pragma unroll
    for (int j = 0; j < 8; j++) pj[j] = pW[(t * 24 + 16 + j) * 8 + f];
    union { _Float16 hh[16]; float4 f4[2]; } u;
#pragma unroll
    for (int k = 0; k < 16; k++) {
        float s = 0.f;
#pragma unroll
        for (int j = 0; j < 8; j++) s += eW[k * 8 + j] * pj[j];
        u.hh[k] = (_Float16)s;
    }
    float c0 = pb[t * 8 + f];
#pragma unroll
    for (int j = 0; j < 8; j++) c0 += eb[j] * pj[j];
    wchp[2 * idx]     = u.f4[0];
    wchp[2 * idx + 1] = u.f4[1];
    abias[idx] = c0;
}

// ---------------- per-layer kernels ----------------

__device__ __forceinline__ unsigned short f2bf_rne(float v) {
    unsigned u = __float_as_uint(v);
    return (unsigned short)((u + 0x7FFFu + ((u >> 16) & 1u)) >> 16);
}

// b16[n][ch] = bf16(preW_xj . xt)   (layer 0 only; later layers fused in epilogue)
__global__ void node_pre(const float* __restrict__ xin,
                         const float* __restrict__ preW,
                         unsigned short* __restrict__ b16) {
    int idx = blockIdx.x * 256 + threadIdx.x;
    if (idx >= NN * F) return;
    int n = idx >> 5, ch = idx & 31;
    int t = ch >> 3, f = ch & 7;
    const float* xrow = xin + n * F + t * FT;
    const float* wB = preW + (t * 24 + 8) * 8 + f;
    float bv = 0.f;
#pragma unroll
    for (int k = 0; k < 8; k++) bv += xrow[k] * wB[k * 8];
    b16[idx] = f2bf_rne(bv);
}

// one wave per dst node. Epilogue weight tables staged in LDS (conflict-free
// [k][ch] layout) -> ~85 per-node lane-varying weight loads move from the
// contended TA/VMEM pipe to the idle LDS pipe. One barrier after staging;
// waves fully independent afterwards (shuffle handoff, no per-node barrier).
__global__ __launch_bounds__(256) void gather_post(
        const float* __restrict__ xin,
        const unsigned short* __restrict__ b16_in,
        unsigned short* __restrict__ b16_out,  // may be nullptr (last layer)
        const float4* __restrict__ eh,         // [NE][2] fp16 eattr, CSR order
        const int* __restrict__ row_ptr, const int* __restrict__ cnt,
        const int* __restrict__ src_s,         // src*F per slot
        const float4* __restrict__ wchp_l,     // [32][2] this layer's packed wc16
        const float* __restrict__ abias_l,     // [32]
        const float* __restrict__ preW,        // [T,24,8]
        const float* __restrict__ postW, const float* __restrict__ postb,
        const float* __restrict__ linW, const float* __restrict__ linb,
        const float* __restrict__ preW_next,   // next layer's [T,24,8] or nullptr
        float* __restrict__ xout) {
    __shared__ float sw[2656];
    float* sPreXi = sw;            // 256:  [j][ch] = preW[(t*24+j)*8+f]
    float* sPost  = sw + 256;      // 1024: [q][ch] = postW[(t*32+q)*8+f]
    float* sLin   = sw + 1280;     // 1024: [k][ch] = linW[k*32+ch]
    float* sPreN  = sw + 2304;     // 256:  [j][ch] = preW_next[(t*24+8+j)*8+f]
    float* sMisc  = sw + 2560;     // 96: abias[ch], postb[ch], linb[ch]
    int tid = threadIdx.x;
    {
        int c = tid & 31, tt = c >> 3, ff = c & 7;
        int j = tid >> 5;
        sPreXi[tid] = preW[(tt * 24 + j) * 8 + ff];
        if (preW_next) sPreN[tid] = preW_next[(tt * 24 + 8 + j) * 8 + ff];
#pragma unroll
        for (int k = tid; k < 1024; k += 256) {
            int q = k >> 5, c2 = k & 31;
            sPost[k] = postW[(((c2 >> 3) * 32 + q)) * 8 + (c2 & 7)];
            sLin[k] = linW[k];
        }
        if (tid < 32) sMisc[tid] = abias_l[tid];
        else if (tid < 64) sMisc[tid] = postb[tid - 32];
        else if (tid < 96) sMisc[tid] = linb[tid - 64];
    }
    __syncthreads();

    int wv = tid >> 6;
    int lane = tid & 63;
    int n = blockIdx.x * 4 + wv;            // NN divisible by 4

    // gather-phase partition: 8 edges (e_sub) x 8 ch-groups (4 ch each)
    int chgrp = lane >> 3;                  // 0..7 -> channels 4*chgrp .. 4*chgrp+3
    int e_sub = lane & 7;
    const unsigned short* bp = b16_in + chgrp * 4;

    union { float4 f4[8]; h2 p[32]; } uw;   // wc16 for this lane's 4 channels
#pragma unroll
    for (int c = 0; c < 4; c++) {
        uw.f4[2 * c]     = wchp_l[2 * (chgrp * 4 + c)];
        uw.f4[2 * c + 1] = wchp_l[2 * (chgrp * 4 + c) + 1];
    }

    int rs = row_ptr[n], deg = cnt[n];
    int re = rs + deg;

    float S[4] = {0.f, 0.f, 0.f, 0.f};
    float M[4] = {-3.4e38f, -3.4e38f, -3.4e38f, -3.4e38f};

    int i0 = rs + e_sub;
    int sA = 0;
    if (i0 < re) sA = src_s[i0];
#pragma unroll 2
    for (int i = i0; i < re; i += 8) {
        int nj = i + 8;
        int sB = src_s[(nj < re) ? nj : i];
        ushort4 b4 = *(const ushort4*)(bp + sA);
        float4 lo = eh[2 * (size_t)i];
        float4 hi = eh[2 * (size_t)i + 1];
        unsigned short bv[4] = {b4.x, b4.y, b4.z, b4.w};
        union { float4 f4; h2 p[4]; } ua, ub;
        ua.f4 = lo; ub.f4 = hi;
#pragma unroll
        for (int c = 0; c < 4; c++) {
            float h = __uint_as_float((unsigned)bv[c] << 16);
            h = dot2(ua.p[0], uw.p[c * 8 + 0], h);
            h = dot2(ua.p[1], uw.p[c * 8 + 1], h);
            h = dot2(ua.p[2], uw.p[c * 8 + 2], h);
            h = dot2(ua.p[3], uw.p[c * 8 + 3], h);
            h = dot2(ub.p[0], uw.p[c * 8 + 4], h);
            h = dot2(ub.p[1], uw.p[c * 8 + 5], h);
            h = dot2(ub.p[2], uw.p[c * 8 + 6], h);
            h = dot2(ub.p[3], uw.p[c * 8 + 7], h);
            S[c] += h;
            M[c] = fmaxf(M[c], h);
        }
        sA = sB;
    }
    // xor-butterfly over the 8 edge-slots
#pragma unroll
    for (int m = 1; m < 8; m <<= 1) {
#pragma unroll
        for (int c = 0; c < 4; c++) {
            S[c] += __shfl_xor(S[c], m, 64);
            M[c] = fmaxf(M[c], __shfl_xor(M[c], m, 64));
        }
    }

    // in-register handoff to ch-per-lane layout (no LDS, no barrier)
    int ch = lane & 31, half = lane >> 5;
    int t = ch >> 3, f = ch & 7;
    int srcl = (ch >> 2) * 8;
    float s0 = __shfl(S[0], srcl, 64), s1 = __shfl(S[1], srcl, 64);
    float s2 = __shfl(S[2], srcl, 64), s3 = __shfl(S[3], srcl, 64);
    float m0 = __shfl(M[0], srcl, 64), m1 = __shfl(M[1], srcl, 64);
    float m2 = __shfl(M[2], srcl, 64), m3 = __shfl(M[3], srcl, 64);
    int r = ch & 3;
    float Sc = (r == 0) ? s0 : (r == 1) ? s1 : (r == 2) ? s2 : s3;
    float Mc = (r == 0) ? m0 : (r == 1) ? m1 : (r == 2) ? m2 : m3;

    float xv = xin[(size_t)n * F + ch];
    // a_val = abias + preW_xi . xt  (weights from LDS, conflict-free)
    float a_val = sMisc[ch];
#pragma unroll
    for (int j = 0; j < 8; j++)
        a_val += __shfl(xv, t * 8 + j, 64) * sPreXi[j * 32 + ch];

    float sum_h, mean_h, max_h;
    if (deg > 0) {
        sum_h = Sc + (float)deg * a_val;
        mean_h = sum_h / (float)deg;
        max_h = Mc + a_val;
    } else {
        sum_h = 0.f; mean_h = 0.f; max_h = 0.f;
    }

    // post-MLP per tower (weights from LDS)
    float ua0 = 0.f, ua1 = 0.f, ua2 = 0.f, ua3 = 0.f;
#pragma unroll
    for (int kk = 0; kk < 8; kk++) {
        int sl = t * 8 + kk;
        ua0 += __shfl(xv,     sl, 64) * sPost[(0 * 8 + kk) * 32 + ch];
        ua1 += __shfl(mean_h, sl, 64) * sPost[(1 * 8 + kk) * 32 + ch];
        ua2 += __shfl(sum_h,  sl, 64) * sPost[(2 * 8 + kk) * 32 + ch];
        ua3 += __shfl(max_h,  sl, 64) * sPost[(3 * 8 + kk) * 32 + ch];
    }
    float u2 = sMisc[32 + ch] + ((ua0 + ua1) + (ua2 + ua3));

    // final mixing linear + relu (weights from LDS) — 4 independent chains
    float y0 = 0.f, y1 = 0.f, y2 = 0.f, y3 = 0.f;
#pragma unroll
    for (int k = 0; k < 8; k++) {
        y0 += __shfl(u2, k,      64) * sLin[k * 32 + ch];
        y1 += __shfl(u2, 8 + k,  64) * sLin[(8 + k) * 32 + ch];
        y2 += __shfl(u2, 16 + k, 64) * sLin[(16 + k) * 32 + ch];
        y3 += __shfl(u2, 24 + k, 64) * sLin[(24 + k) * 32 + ch];
    }
    float y = sMisc[64 + ch] + ((y0 + y1) + (y2 + y3));
    y = fmaxf(y, 0.f);
    if (half == 0)
        xout[(size_t)n * F + ch] = y;

    // fused node_pre for next layer -> DIFFERENT buffer (no race)
    if (preW_next) {
        float bn = 0.f;
#pragma unroll
        for (int j = 0; j < 8; j++)
            bn += __shfl(y, t * 8 + j, 64) * sPreN[j * 32 + ch];
        if (half == 0)
            b16_out[(size_t)n * F + ch] = f2bf_rne(bn);
    }
}

// ---------------- launch ----------------

extern "C" void kernel_launch(void* const* d_in, const int* in_sizes, int n_in,
                              void* d_out, int out_size, void* d_ws, size_t ws_size,
                              hipStream_t stream) {
    const float* x      = (const float*)d_in[0];
    const int*   ei     = (const int*)d_in[1];
    const float* eattr  = (const float*)d_in[2];
    const float* edge_W = (const float*)d_in[3];
    const float* edge_b = (const float*)d_in[4];
    const float* pre_W  = (const float*)d_in[5];
    const float* pre_b  = (const float*)d_in[6];
    const float* post_W = (const float*)d_in[7];
    const float* post_b = (const float*)d_in[8];
    const float* lin_W  = (const float*)d_in[9];
    const float* lin_b  = (const float*)d_in[10];
    float* out = (float*)d_out;

    const size_t NC = (size_t)NN * F;
    char* p = (char*)d_ws;
    float4* eh    = (float4*)p;        p += sizeof(float4) * 2 * (size_t)NE;  // 51.2 MB
    int* src_s    = (int*)p;           p += sizeof(int) * NE;
    int* cnt      = (int*)p;           p += sizeof(int) * NN;
    int* row_ptr  = (int*)p;           p += sizeof(int) * NN;
    int* cursor   = (int*)p;           p += sizeof(int) * NN;
    unsigned short* b16a = (unsigned short*)p;  p += sizeof(unsigned short) * NC;
    unsigned short* b16b = (unsigned short*)p;  p += sizeof(unsigned short) * NC;
    float* xb0    = (float*)p;         p += sizeof(float) * NC;
    float* xb1    = (float*)p;         p += sizeof(float) * NC;
    float4* wchp  = (float4*)p;        p += sizeof(float4) * 2 * NLAYERS * 32;
    float* abias  = (float*)p;         p += sizeof(float) * NLAYERS * 32;

    dim3 blk(256);
    int gN  = (NN + 255) / 256;
    int gE  = (NE + 255) / 256;
    int gNC = (NN * F + 255) / 256;
    int gG  = NN / 4;

    // CSR build + fp16 eattr permute + layer constants (once)
    hipLaunchKernelGGL(zero_cnt,     dim3(gN), blk, 0, stream, cnt);
    hipLaunchKernelGGL(count_kernel, dim3(gE), blk, 0, stream, ei, cnt);
    hipLaunchKernelGGL(scan_kernel,  dim3(1), dim3(1024), 0, stream, cnt, row_ptr, cursor);
    hipLaunchKernelGGL(build_kernel, dim3(gE), blk, 0, stream, ei, eattr,
                       cursor, src_s, eh);
    hipLaunchKernelGGL(layer_const,  dim3(1), blk, 0, stream,
                       edge_W, edge_b, pre_W, pre_b, wchp, abias);

    // layer 0's b16
    hipLaunchKernelGGL(node_pre, dim3(gNC), blk, 0, stream, x, pre_W, b16a);

    const float* xin = x;
    for (int l = 0; l < NLAYERS; l++) {
        const float* pW  = pre_W  + (size_t)l * T * 24 * FT;
        const float* poW = post_W + (size_t)l * T * 32 * FT;
        const float* pob = post_b + (size_t)l * T * FT;
        const float* lW  = lin_W  + (size_t)l * F * F;
        const float* lb  = lin_b  + (size_t)l * F;
        const float* pWn = (l + 1 < NLAYERS) ? (pre_W + (size_t)(l + 1) * T * 24 * FT)
                                             : nullptr;
        float* xout = (l == NLAYERS - 1) ? out : ((l & 1) ? xb1 : xb0);
        const unsigned short* bin  = (l & 1) ? b16b : b16a;
        unsigned short*       bout = (l & 1) ? b16a : b16b;

        hipLaunchKernelGGL(gather_post, dim3(gG), blk, 0, stream,
                           xin, bin, pWn ? bout : nullptr, eh, row_ptr, cnt, src_s,
                           wchp + (size_t)l * 64, abias + (size_t)l * 32,
                           pW, poW, pob, lW, lb, pWn, xout);
        xin = xout;
    }
}

// Round 26
// 690.007 us; speedup vs baseline: 1.0254x; 1.0254x over previous
//
#include <hip/hip_runtime.h>
#include <hip/hip_fp16.h>

#define NN 50000
#define NE 1600000
#define F 32
#define T 4
#define FT 8
#define ED 16
#define NLAYERS 5

typedef _Float16 h2 __attribute__((ext_vector_type(2)));

__device__ __forceinline__ float dot2(h2 a, h2 b, float c) {
#if __has_builtin(__builtin_amdgcn_fdot2)
    return __builtin_amdgcn_fdot2(a, b, c, false);
#else
    return c + (float)a.x * (float)b.x + (float)a.y * (float)b.y;
#endif
}

// ---------------- CSR build (once per call; edge_index constant across layers) ----

__global__ void zero_cnt(int* __restrict__ cnt) {
    int i = blockIdx.x * 256 + threadIdx.x;
    if (i < NN) cnt[i] = 0;
}

__global__ void count_kernel(const int* __restrict__ ei, int* __restrict__ cnt) {
    int e = blockIdx.x * 256 + threadIdx.x;
    if (e >= NE) return;
    atomicAdd(&cnt[ei[NE + e]], 1);
}

// one-block exclusive scan over cnt[NN] -> row_ptr, cursor (1024 threads)
__global__ void scan_kernel(const int* __restrict__ cnt, int* __restrict__ row_ptr,
                            int* __restrict__ cursor) {
    __shared__ int wsum[16];
    __shared__ int carry_s;
    int tid = threadIdx.x;
    int lane = tid & 63, wid = tid >> 6;
    if (tid == 0) carry_s = 0;
    __syncthreads();
    for (int base = 0; base < NN; base += 1024) {
        int i = base + tid;
        int v = (i < NN) ? cnt[i] : 0;
        int s = v;
#pragma unroll
        for (int off = 1; off < 64; off <<= 1) {
            int tt = __shfl_up(s, off, 64);
            if (lane >= off) s += tt;
        }
        __syncthreads();
        if (lane == 63) wsum[wid] = s;
        __syncthreads();
        if (wid == 0 && lane < 16) {
            int w = wsum[lane];
            int ws = w;
#pragma unroll
            for (int off = 1; off < 16; off <<= 1) {
                int tt = __shfl_up(ws, off, 16);
                if (lane >= off) ws += tt;
            }
            wsum[lane] = ws - w;
        }
        __syncthreads();
        int excl = carry_s + wsum[wid] + s - v;
        if (i < NN) { row_ptr[i] = excl; cursor[i] = excl; }
        __syncthreads();
        if (tid == 1023) carry_s += wsum[15] + s;
    }
}

// fused scatter: read eattr SEQUENTIALLY, compute CSR slot p, write src*32 + fp16 eattr.
__global__ void build_kernel(const int* __restrict__ ei,
                             const float* __restrict__ eattr,
                             int* __restrict__ cursor,
                             int* __restrict__ src_s,     // stores src*F (element offset)
                             float4* __restrict__ eh) {   // [NE][2] float4 (=16 half)
    int e = blockIdx.x * 256 + threadIdx.x;
    if (e >= NE) return;
    int src = ei[e];
    int dst = ei[NE + e];
    const float4* eap = (const float4*)(eattr + (size_t)e * ED);
    float4 v0 = eap[0], v1 = eap[1], v2 = eap[2], v3 = eap[3];
    union { __half hh[16]; float4 f4[2]; } u;
    u.hh[0]  = __float2half(v0.x); u.hh[1]  = __float2half(v0.y);
    u.hh[2]  = __float2half(v0.z); u.hh[3]  = __float2half(v0.w);
    u.hh[4]  = __float2half(v1.x); u.hh[5]  = __float2half(v1.y);
    u.hh[6]  = __float2half(v1.z); u.hh[7]  = __float2half(v1.w);
    u.hh[8]  = __float2half(v2.x); u.hh[9]  = __float2half(v2.y);
    u.hh[10] = __float2half(v2.z); u.hh[11] = __float2half(v2.w);
    u.hh[12] = __float2half(v3.x); u.hh[13] = __float2half(v3.y);
    u.hh[14] = __float2half(v3.z); u.hh[15] = __float2half(v3.w);
    int p = atomicAdd(&cursor[dst], 1);
    src_s[p] = src << 5;   // src * F
    eh[2 * (size_t)p]     = u.f4[0];
    eh[2 * (size_t)p + 1] = u.f4[1];
}

// per-layer constants: wchp[(l*32+ch)] = packed fp16 wc16 (16 halfs = 2 float4);
// abias[l*32+ch] = preb + ebias . preW_ee
__global__ void layer_const(const float* __restrict__ edge_W,  // [L,16,8]
                            const float* __restrict__ edge_b,  // [L,8]
                            const float* __restrict__ pre_W,   // [L,T,24,8]
                            const float* __restrict__ pre_b,   // [L,T,8]
                            float4* __restrict__ wchp,         // [L*32][2]
                            float* __restrict__ abias) {       // [L*32]
    int idx = threadIdx.x;
    if (idx >= NLAYERS * 32) return;
    int l = idx >> 5, ch = idx & 31;
    int t = ch >> 3, f = ch & 7;
    const float* eW = edge_W + (size_t)l * ED * FT;
    const float* eb = edge_b + (size_t)l * FT;
    const float* pW = pre_W + (size_t)l * T * 24 * FT;
    const float* pb = pre_b + (size_t)l * T * FT;
    float pj[8];
#pragma unroll
    for (int j = 0; j < 8; j++) pj[j] = pW[(t * 24 + 16 + j) * 8 + f];
    union { _Float16 hh[16]; float4 f4[2]; } u;
#pragma unroll
    for (int k = 0; k < 16; k++) {
        float s = 0.f;
#pragma unroll
        for (int j = 0; j < 8; j++) s += eW[k * 8 + j] * pj[j];
        u.hh[k] = (_Float16)s;
    }
    float c0 = pb[t * 8 + f];
#pragma unroll
    for (int j = 0; j < 8; j++) c0 += eb[j] * pj[j];
    wchp[2 * idx]     = u.f4[0];
    wchp[2 * idx + 1] = u.f4[1];
    abias[idx] = c0;
}

// ---------------- per-layer kernels ----------------

__device__ __forceinline__ unsigned short f2bf_rne(float v) {
    unsigned u = __float_as_uint(v);
    return (unsigned short)((u + 0x7FFFu + ((u >> 16) & 1u)) >> 16);
}

// b16[n][ch] = bf16(preW_xj . xt)   (layer 0 only; later layers fused in epilogue)
__global__ void node_pre(const float* __restrict__ xin,
                         const float* __restrict__ preW,
                         unsigned short* __restrict__ b16) {
    int idx = blockIdx.x * 256 + threadIdx.x;
    if (idx >= NN * F) return;
    int n = idx >> 5, ch = idx & 31;
    int t = ch >> 3, f = ch & 7;
    const float* xrow = xin + n * F + t * FT;
    const float* wB = preW + (t * 24 + 8) * 8 + f;
    float bv = 0.f;
#pragma unroll
    for (int k = 0; k < 8; k++) bv += xrow[k] * wB[k * 8];
    b16[idx] = f2bf_rne(bv);
}

// one wave per dst node, waves FULLY independent (no LDS, no __syncthreads):
// gather partition 8 edges x 8 ch-groups (4 ch/lane); xor-butterfly reduce over
// e_sub leaves the reduced S[4]/M[4] in EVERY lane of the 8-lane group; the
// epilogue remaps to ch-per-lane with 8 shuffles + selects (no barrier drain,
// no inter-wave tail coupling).
__global__ __launch_bounds__(256) void gather_post(
        const float* __restrict__ xin,
        const unsigned short* __restrict__ b16_in,
        unsigned short* __restrict__ b16_out,  // may be nullptr (last layer)
        const float4* __restrict__ eh,         // [NE][2] fp16 eattr, CSR order
        const int* __restrict__ row_ptr, const int* __restrict__ cnt,
        const int* __restrict__ src_s,         // src*F per slot
        const float4* __restrict__ wchp_l,     // [32][2] this layer's packed wc16
        const float* __restrict__ abias_l,     // [32]
        const float* __restrict__ preW,        // [T,24,8]
        const float* __restrict__ postW, const float* __restrict__ postb,
        const float* __restrict__ linW, const float* __restrict__ linb,
        const float* __restrict__ preW_next,   // next layer's [T,24,8] or nullptr
        float* __restrict__ xout) {
    int tid = threadIdx.x;
    int wv = tid >> 6;
    int lane = tid & 63;
    int n = blockIdx.x * 4 + wv;            // NN divisible by 4

    // gather-phase partition: 8 edges (e_sub) x 8 ch-groups (4 ch each)
    int chgrp = lane >> 3;                  // 0..7 -> channels 4*chgrp .. 4*chgrp+3
    int e_sub = lane & 7;
    const unsigned short* bp = b16_in + chgrp * 4;

    union { float4 f4[8]; h2 p[32]; } uw;   // wc16 for this lane's 4 channels
#pragma unroll
    for (int c = 0; c < 4; c++) {
        uw.f4[2 * c]     = wchp_l[2 * (chgrp * 4 + c)];
        uw.f4[2 * c + 1] = wchp_l[2 * (chgrp * 4 + c) + 1];
    }

    int rs = row_ptr[n], deg = cnt[n];
    int re = rs + deg;

    float S[4] = {0.f, 0.f, 0.f, 0.f};
    float M[4] = {-3.4e38f, -3.4e38f, -3.4e38f, -3.4e38f};

    int i0 = rs + e_sub;
    int sA = 0;
    if (i0 < re) sA = src_s[i0];
#pragma unroll 2
    for (int i = i0; i < re; i += 8) {
        int nj = i + 8;
        int sB = src_s[(nj < re) ? nj : i];
        ushort4 b4 = *(const ushort4*)(bp + sA);
        float4 lo = eh[2 * (size_t)i];
        float4 hi = eh[2 * (size_t)i + 1];
        unsigned short bv[4] = {b4.x, b4.y, b4.z, b4.w};
        union { float4 f4; h2 p[4]; } ua, ub;
        ua.f4 = lo; ub.f4 = hi;
#pragma unroll
        for (int c = 0; c < 4; c++) {
            float h = __uint_as_float((unsigned)bv[c] << 16);
            h = dot2(ua.p[0], uw.p[c * 8 + 0], h);
            h = dot2(ua.p[1], uw.p[c * 8 + 1], h);
            h = dot2(ua.p[2], uw.p[c * 8 + 2], h);
            h = dot2(ua.p[3], uw.p[c * 8 + 3], h);
            h = dot2(ub.p[0], uw.p[c * 8 + 4], h);
            h = dot2(ub.p[1], uw.p[c * 8 + 5], h);
            h = dot2(ub.p[2], uw.p[c * 8 + 6], h);
            h = dot2(ub.p[3], uw.p[c * 8 + 7], h);
            S[c] += h;
            M[c] = fmaxf(M[c], h);
        }
        sA = sB;
    }
    // xor-butterfly over the 8 edge-slots: afterwards EVERY lane of the 8-lane
    // group holds the fully reduced S[4]/M[4] for its group's 4 channels.
#pragma unroll
    for (int m = 1; m < 8; m <<= 1) {
#pragma unroll
        for (int c = 0; c < 4; c++) {
            S[c] += __shfl_xor(S[c], m, 64);
            M[c] = fmaxf(M[c], __shfl_xor(M[c], m, 64));
        }
    }

    // in-register handoff to ch-per-lane layout (no LDS, no barrier):
    // lane wants channel ch=lane&31 -> group g=ch>>2 (lanes 8g..8g+7), reg ch&3.
    int ch = lane & 31, half = lane >> 5;
    int t = ch >> 3, f = ch & 7;
    int srcl = (ch >> 2) * 8;
    float s0 = __shfl(S[0], srcl, 64), s1 = __shfl(S[1], srcl, 64);
    float s2 = __shfl(S[2], srcl, 64), s3 = __shfl(S[3], srcl, 64);
    float m0 = __shfl(M[0], srcl, 64), m1 = __shfl(M[1], srcl, 64);
    float m2 = __shfl(M[2], srcl, 64), m3 = __shfl(M[3], srcl, 64);
    int r = ch & 3;
    float Sc = (r == 0) ? s0 : (r == 1) ? s1 : (r == 2) ? s2 : s3;
    float Mc = (r == 0) ? m0 : (r == 1) ? m1 : (r == 2) ? m2 : m3;

    float xv = xin[(size_t)n * F + ch];
    // a_val = abias + preW_xi . xt  (own node, via shuffles of xv)
    float a_val = abias_l[ch];
#pragma unroll
    for (int j = 0; j < 8; j++)
        a_val += __shfl(xv, t * 8 + j, 64) * preW[(t * 24 + j) * 8 + f];

    float sum_h, mean_h, max_h;
    if (deg > 0) {
        sum_h = Sc + (float)deg * a_val;
        mean_h = sum_h / (float)deg;
        max_h = Mc + a_val;
    } else {
        sum_h = 0.f; mean_h = 0.f; max_h = 0.f;
    }

    // post-MLP per tower: u = postb + [xt|mean|sum|max] @ postW   (via shuffles)
    float ua0 = 0.f, ua1 = 0.f, ua2 = 0.f, ua3 = 0.f;
#pragma unroll
    for (int kk = 0; kk < 8; kk++) {
        int sl = t * 8 + kk;
        ua0 += __shfl(xv,     sl, 64) * postW[(t * 32 + 0 * 8 + kk) * 8 + f];
        ua1 += __shfl(mean_h, sl, 64) * postW[(t * 32 + 1 * 8 + kk) * 8 + f];
        ua2 += __shfl(sum_h,  sl, 64) * postW[(t * 32 + 2 * 8 + kk) * 8 + f];
        ua3 += __shfl(max_h,  sl, 64) * postW[(t * 32 + 3 * 8 + kk) * 8 + f];
    }
    float u2 = postb[t * 8 + f] + ((ua0 + ua1) + (ua2 + ua3));

    // final mixing linear + relu — 4 independent chains
    float y0 = 0.f, y1 = 0.f, y2 = 0.f, y3 = 0.f;
#pragma unroll
    for (int k = 0; k < 8; k++) {
        y0 += __shfl(u2, k,      64) * linW[k * 32 + ch];
        y1 += __shfl(u2, 8 + k,  64) * linW[(8 + k) * 32 + ch];
        y2 += __shfl(u2, 16 + k, 64) * linW[(16 + k) * 32 + ch];
        y3 += __shfl(u2, 24 + k, 64) * linW[(24 + k) * 32 + ch];
    }
    float y = linb[ch] + ((y0 + y1) + (y2 + y3));
    y = fmaxf(y, 0.f);
    if (half == 0)
        xout[(size_t)n * F + ch] = y;

    // fused node_pre for next layer -> DIFFERENT buffer (no race)
    if (preW_next) {
        float bn = 0.f;
#pragma unroll
        for (int j = 0; j < 8; j++)
            bn += __shfl(y, t * 8 + j, 64) * preW_next[(t * 24 + 8 + j) * 8 + f];
        if (half == 0)
            b16_out[(size_t)n * F + ch] = f2bf_rne(bn);
    }
}

// ---------------- launch ----------------

extern "C" void kernel_launch(void* const* d_in, const int* in_sizes, int n_in,
                              void* d_out, int out_size, void* d_ws, size_t ws_size,
                              hipStream_t stream) {
    const float* x      = (const float*)d_in[0];
    const int*   ei     = (const int*)d_in[1];
    const float* eattr  = (const float*)d_in[2];
    const float* edge_W = (const float*)d_in[3];
    const float* edge_b = (const float*)d_in[4];
    const float* pre_W  = (const float*)d_in[5];
    const float* pre_b  = (const float*)d_in[6];
    const float* post_W = (const float*)d_in[7];
    const float* post_b = (const float*)d_in[8];
    const float* lin_W  = (const float*)d_in[9];
    const float* lin_b  = (const float*)d_in[10];
    float* out = (float*)d_out;

    const size_t NC = (size_t)NN * F;
    char* p = (char*)d_ws;
    float4* eh    = (float4*)p;        p += sizeof(float4) * 2 * (size_t)NE;  // 51.2 MB
    int* src_s    = (int*)p;           p += sizeof(int) * NE;
    int* cnt      = (int*)p;           p += sizeof(int) * NN;
    int* row_ptr  = (int*)p;           p += sizeof(int) * NN;
    int* cursor   = (int*)p;           p += sizeof(int) * NN;
    unsigned short* b16a = (unsigned short*)p;  p += sizeof(unsigned short) * NC;
    unsigned short* b16b = (unsigned short*)p;  p += sizeof(unsigned short) * NC;
    float* xb0    = (float*)p;         p += sizeof(float) * NC;
    float* xb1    = (float*)p;         p += sizeof(float) * NC;
    float4* wchp  = (float4*)p;        p += sizeof(float4) * 2 * NLAYERS * 32;
    float* abias  = (float*)p;         p += sizeof(float) * NLAYERS * 32;

    dim3 blk(256);
    int gN  = (NN + 255) / 256;
    int gE  = (NE + 255) / 256;
    int gNC = (NN * F + 255) / 256;
    int gG  = NN / 4;

    // CSR build + fp16 eattr permute + layer constants (once)
    hipLaunchKernelGGL(zero_cnt,     dim3(gN), blk, 0, stream, cnt);
    hipLaunchKernelGGL(count_kernel, dim3(gE), blk, 0, stream, ei, cnt);
    hipLaunchKernelGGL(scan_kernel,  dim3(1), dim3(1024), 0, stream, cnt, row_ptr, cursor);
    hipLaunchKernelGGL(build_kernel, dim3(gE), blk, 0, stream, ei, eattr,
                       cursor, src_s, eh);
    hipLaunchKernelGGL(layer_const,  dim3(1), blk, 0, stream,
                       edge_W, edge_b, pre_W, pre_b, wchp, abias);

    // layer 0's b16
    hipLaunchKernelGGL(node_pre, dim3(gNC), blk, 0, stream, x, pre_W, b16a);

    const float* xin = x;
    for (int l = 0; l < NLAYERS; l++) {
        const float* pW  = pre_W  + (size_t)l * T * 24 * FT;
        const float* poW = post_W + (size_t)l * T * 32 * FT;
        const float* pob = post_b + (size_t)l * T * FT;
        const float* lW  = lin_W  + (size_t)l * F * F;
        const float* lb  = lin_b  + (size_t)l * F;
        const float* pWn = (l + 1 < NLAYERS) ? (pre_W + (size_t)(l + 1) * T * 24 * FT)
                                             : nullptr;
        float* xout = (l == NLAYERS - 1) ? out : ((l & 1) ? xb1 : xb0);
        const unsigned short* bin  = (l & 1) ? b16b : b16a;
        unsigned short*       bout = (l & 1) ? b16a : b16b;

        hipLaunchKernelGGL(gather_post, dim3(gG), blk, 0, stream,
                           xin, bin, pWn ? bout : nullptr, eh, row_ptr, cnt, src_s,
                           wchp + (size_t)l * 64, abias + (size_t)l * 32,
                           pW, poW, pob, lW, lb, pWn, xout);
        xin = xout;
    }
}